// Round 11
// baseline (444.104 us; speedup 1.0000x reference)
//
#include <hip/hip_runtime.h>

// Problem constants
#define NSAMP 262144
#define CCLS 128
#define DDIM 256
#define EPSF 1e-8f

// ws byte offsets
#define OFF_COUNTS 0u         // 128 * u32
#define OFF_SUMS   2048u      // 128x256 f32 sums (slot-permuted)
#define OFF_G      133120u    // 128x128 f32
#define OFF_W      198656u    // 128x128 f32 (G^-1)
#define OFF_TT     264192u    // 256x128 f32 (T transposed)
#define OFF_B      395264u    // 128x128 f32 (means @ T^T)
#define OFF_ZT     460800u    // 128x128 f32 (W @ B^T)
#define OFF_M      526336u    // 128x128 f32 (B W B^T)
#define OFF_BIG    1644288u   // slabs: 256 x 32768 f32 (128KB each) = 33.5 MB

// ---------------------------------------------------------------------------
// KG: 4 blocks x 1024. Block g computes rows [32g,32g+32) of G = T*T^T and
//     writes T^T chunk g. (verbatim verified)
// ---------------------------------------------------------------------------
extern "C" __global__ __launch_bounds__(1024)
void kg_gram(const float* __restrict__ T, char* __restrict__ ws)
{
    __shared__ float Tl[64][132];
    const int g = blockIdx.x, tid = threadIdx.x;
    float* Tt = (float*)(ws + OFF_TT);
    float* G  = (float*)(ws + OFF_G);
    float a0[8], a1[8];
    #pragma unroll
    for (int j = 0; j < 8; ++j) { a0[j] = 0.f; a1[j] = 0.f; }
    const int Lr = 2 * (tid >> 4);
    const int c0 = 8 * (tid & 15);
    for (int ch = 0; ch < 4; ++ch) {
        for (int i = tid; i < 8192; i += 1024) {
            int cc = i >> 6, dd = i & 63;
            Tl[dd][cc] = T[cc * 256 + ch * 64 + dd];
        }
        __syncthreads();
        if (g == ch) {
            for (int i = tid; i < 8192; i += 1024) {
                int c2 = i & 127, d2 = i >> 7;
                Tt[(ch * 64 + d2) * 128 + c2] = Tl[d2][c2];
            }
        }
        if (tid < 256) {
            for (int dd = 0; dd < 64; ++dd) {
                float r0 = Tl[dd][32 * g + Lr];
                float r1 = Tl[dd][32 * g + Lr + 1];
                float cv[8];
                *(float4*)&cv[0] = *(const float4*)&Tl[dd][c0];
                *(float4*)&cv[4] = *(const float4*)&Tl[dd][c0 + 4];
                #pragma unroll
                for (int j = 0; j < 8; ++j) { a0[j] += r0 * cv[j]; a1[j] += r1 * cv[j]; }
            }
        }
        __syncthreads();
    }
    if (tid < 256) {
        int gr = 32 * g + Lr;
        *(float4*)&G[gr * 128 + c0]           = make_float4(a0[0], a0[1], a0[2], a0[3]);
        *(float4*)&G[gr * 128 + c0 + 4]       = make_float4(a0[4], a0[5], a0[6], a0[7]);
        *(float4*)&G[(gr + 1) * 128 + c0]     = make_float4(a1[0], a1[1], a1[2], a1[3]);
        *(float4*)&G[(gr + 1) * 128 + c0 + 4] = make_float4(a1[4], a1[5], a1[6], a1[7]);
    }
}

// ---------------------------------------------------------------------------
// KX: blocks 0..255: fused gated argmax + segment-sum (single pass over
//     sample data; each gated sample's logits row (512B) + img row (1KB)
//     read exactly once; ungated rows never read). 3-deep wave-uniform
//     pipeline; 64-lane butterfly argmax; conflict-free permuted LDS acc
//     (dim 4L+j -> slot j*64+L); flush = plain float4 stores to own slab.
//     Block 256: Gauss-Jordan inversion of G -> W, 4x4 tile/thread
//     (gg = 16 VGPR << any occupancy cap -> cannot spill; the 8x8 variant
//     spilled whenever co-located, r3/r7).
// ---------------------------------------------------------------------------
extern "C" __global__ __launch_bounds__(1024)
void kx(const float* __restrict__ logits, const float* __restrict__ img,
        const void* __restrict__ mask, char* __restrict__ ws, int nSlab)
{
    __shared__ float acc[CCLS][DDIM];   // 128 KB; kinv block aliases rows 0..3
    const int tid = threadIdx.x;

    if (blockIdx.x == 256) {
        // ---- Gauss-Jordan inversion, 1024 threads, 4x4 tiles ----
        float* prA = acc[0]; float* prB = acc[1];
        float* pcA = acc[2]; float* pcB = acc[3];
        const float* G = (const float*)(ws + OFF_G);
        float* W = (float*)(ws + OFF_W);
        float gg[4][4];
        const int r0 = 4 * (tid >> 5), c0 = 4 * (tid & 31);
        #pragma unroll
        for (int ii = 0; ii < 4; ++ii)
            *(float4*)&gg[ii][0] = *(const float4*)&G[(r0 + ii) * 128 + c0];
        if (r0 == 0) {
            #pragma unroll
            for (int j = 0; j < 4; ++j) prA[c0 + j] = gg[0][j];
        }
        if (c0 == 0) {
            #pragma unroll
            for (int i = 0; i < 4; ++i) pcA[r0 + i] = gg[i][0];
        }
        __syncthreads();
        for (int k = 0; k < 128; ++k) {
            const float* pr = (k & 1) ? prB : prA;
            const float* pc = (k & 1) ? pcB : pcA;
            float rinv = 1.0f / pr[k];
            float4 ra = *(const float4*)&pr[c0];
            float4 fa = *(const float4*)&pc[r0];
            float rf[4] = { ra.x, ra.y, ra.z, ra.w };
            float fcv[4] = { fa.x, fa.y, fa.z, fa.w };
            #pragma unroll
            for (int j = 0; j < 4; ++j) rf[j] = (c0 + j == k) ? rinv : rf[j] * rinv;
            #pragma unroll
            for (int i = 0; i < 4; ++i) {
                if (r0 + i == k) {
                    #pragma unroll
                    for (int j = 0; j < 4; ++j) gg[i][j] = rf[j];
                } else {
                    float f = fcv[i];
                    #pragma unroll
                    for (int j = 0; j < 4; ++j) {
                        float base = (c0 + j == k) ? 0.0f : gg[i][j];
                        gg[i][j] = base - f * rf[j];
                    }
                }
            }
            const int kn = k + 1;
            if (kn < 128) {
                float* prn = (kn & 1) ? prB : prA;
                float* pcn = (kn & 1) ? pcB : pcA;
                #pragma unroll
                for (int ii = 0; ii < 4; ++ii) {
                    if (r0 + ii == kn) {
                        #pragma unroll
                        for (int j = 0; j < 4; ++j) prn[c0 + j] = gg[ii][j];
                    }
                }
                #pragma unroll
                for (int jj = 0; jj < 4; ++jj) {
                    if (c0 + jj == kn) {
                        #pragma unroll
                        for (int i = 0; i < 4; ++i) pcn[r0 + i] = gg[i][jj];
                    }
                }
            }
            __syncthreads();
        }
        #pragma unroll
        for (int ii = 0; ii < 4; ++ii)
            *(float4*)&W[(r0 + ii) * 128 + c0] = *(float4*)&gg[ii][0];
        return;
    }

    // ---- fused seg blocks ----
    __shared__ int cnts[CCLS];
    __shared__ int sIsBool;
    const int b = blockIdx.x;
    { // init
        float4 z = make_float4(0.f, 0.f, 0.f, 0.f);
        for (int i = tid; i < 8192; i += 1024) ((float4*)acc)[i] = z;
        if (tid < CCLS) cnts[tid] = 0;
        int v = 0;
        if (tid < 64) v = ((const int*)mask)[tid];
        unsigned long long bal = __ballot((unsigned)v > 1u);
        if (tid == 0) sIsBool = (bal != 0ull);
    }
    __syncthreads();
    const bool isBool = (sIsBool != 0);

    const int wave = tid >> 6, lane = tid & 63;
    const int s0 = b * 1024 + wave * 64;
    const float2* lg2 = (const float2*)logits;   // 64 float2 per row
    const float4* im4 = (const float4*)img;      // 64 float4 per row

    int myGate = isBool ? (int)((const unsigned char*)mask)[s0 + lane]
                        : ((const int*)mask)[s0 + lane];
    unsigned long long gm = __ballot(myGate != 0);

    // 3-deep wave-uniform pipeline over gated samples
    int ta = -1, tb = -1, tc = -1;
    float2 la, lb, lc2; float4 va, vb, vc;
    if (gm) {
        ta = (int)(__ffsll((long long)gm) - 1); gm &= gm - 1;
        la = lg2[(size_t)(s0 + ta) * 64 + lane];
        va = im4[(size_t)(s0 + ta) * 64 + lane];
    }
    if (gm) {
        tb = (int)(__ffsll((long long)gm) - 1); gm &= gm - 1;
        lb = lg2[(size_t)(s0 + tb) * 64 + lane];
        vb = im4[(size_t)(s0 + tb) * 64 + lane];
    }
    if (gm) {
        tc = (int)(__ffsll((long long)gm) - 1); gm &= gm - 1;
        lc2 = lg2[(size_t)(s0 + tc) * 64 + lane];
        vc = im4[(size_t)(s0 + tc) * 64 + lane];
    }
    while (ta >= 0) {
        float2 lg = la; float4 v = va;
        ta = tb; la = lb; va = vb;
        tb = tc; lb = lc2; vb = vc;
        tc = -1;
        if (gm) {
            tc = (int)(__ffsll((long long)gm) - 1); gm &= gm - 1;
            lc2 = lg2[(size_t)(s0 + tc) * 64 + lane];
            vc = im4[(size_t)(s0 + tc) * 64 + lane];
        }
        // 64-lane argmax (lane holds dims 2L, 2L+1); smaller dim wins ties
        float m = lg.x; int id = 2 * lane;
        if (lg.y > m) { m = lg.y; id = 2 * lane + 1; }
        #pragma unroll
        for (int off = 1; off < 64; off <<= 1) {
            float om = __shfl_xor(m, off);
            int   oi = __shfl_xor(id, off);
            if (om > m || (om == m && oi < id)) { m = om; id = oi; }
        }
        // accumulate (permuted layout: dim 4L+j -> slot j*64+L, conflict-free)
        atomicAdd(&acc[id][lane],       v.x);
        atomicAdd(&acc[id][64 + lane],  v.y);
        atomicAdd(&acc[id][128 + lane], v.z);
        atomicAdd(&acc[id][192 + lane], v.w);
        if (lane == 0) atomicAdd(&cnts[id], 1);
    }
    __syncthreads();

    const float* accF = &acc[0][0];
    if (nSlab == 256) {
        float4* pp = (float4*)((float*)(ws + OFF_BIG) + (size_t)b * 32768);
        for (int i = tid; i < 8192; i += 1024) pp[i] = ((const float4*)accF)[i];
    } else {
        float* slab = (float*)(ws + OFF_BIG) + (size_t)(b % nSlab) * 32768;
        for (int i = tid; i < 32768; i += 1024)
            if (accF[i] != 0.f) unsafeAtomicAdd(&slab[i], accF[i]);
    }
    if (tid < CCLS && cnts[tid]) atomicAdd(&((int*)(ws + OFF_COUNTS))[tid], cnts[tid]);
}

// ---------------------------------------------------------------------------
// KR: deterministic slab reduction -> sums (slot-permuted). 256 blk x 128 thr.
// ---------------------------------------------------------------------------
extern "C" __global__ __launch_bounds__(128)
void kr_sums(char* __restrict__ ws, int nSlab)
{
    const int idx = blockIdx.x * 128 + threadIdx.x;   // [0, 32768)
    const float* p = (const float*)(ws + OFF_BIG) + idx;
    float a = 0.f;
    for (int r = 0; r < nSlab; ++r) a += p[(size_t)r * 32768];
    ((float*)(ws + OFF_SUMS))[idx] = a;
}

// K4: B = (sums/counts) @ T^T  (mean-divide fused; unpermutes slot layout:
//     slot s -> dim 4*(s&63) + (s>>6))
extern "C" __global__ __launch_bounds__(128)
void k4_B(char* __restrict__ ws)
{
    __shared__ float mr[256];
    const int c = blockIdx.x, j = threadIdx.x;
    const float* sums = (const float*)(ws + OFF_SUMS);
    const int* counts = (const int*)(ws + OFF_COUNTS);
    const float* Tt = (const float*)(ws + OFF_TT);
    float rcp = 1.0f / fmaxf((float)counts[c], 1.0f);
    int s0 = j, s1 = j + 128;
    mr[4 * (s0 & 63) + (s0 >> 6)] = sums[c * 256 + s0] * rcp;
    mr[4 * (s1 & 63) + (s1 >> 6)] = sums[c * 256 + s1] * rcp;
    __syncthreads();
    float a = 0.f;
    #pragma unroll 8
    for (int d = 0; d < 256; ++d) a += mr[d] * Tt[d * 128 + j];
    ((float*)(ws + OFF_B))[c * 128 + j] = a;
}

// K5: Zt = (B @ W)^T = W @ B^T   (W symmetric)
extern "C" __global__ __launch_bounds__(128)
void k5_Z(char* __restrict__ ws)
{
    __shared__ float bc[128];
    const int c = blockIdx.x, j = threadIdx.x;
    const float* B = (const float*)(ws + OFF_B);
    const float* W = (const float*)(ws + OFF_W);
    bc[j] = B[c * 128 + j];
    __syncthreads();
    float a = 0.f;
    #pragma unroll 8
    for (int k = 0; k < 128; ++k) a += bc[k] * W[k * 128 + j];
    ((float*)(ws + OFF_ZT))[j * 128 + c] = a;
}

// K6: M = B @ Zt = B W B^T
extern "C" __global__ __launch_bounds__(128)
void k6_M(char* __restrict__ ws)
{
    __shared__ float bc[128];
    const int c = blockIdx.x, j = threadIdx.x;
    const float* B = (const float*)(ws + OFF_B);
    const float* Zt = (const float*)(ws + OFF_ZT);
    bc[j] = B[c * 128 + j];
    __syncthreads();
    float a = 0.f;
    #pragma unroll 8
    for (int k = 0; k < 128; ++k) a += bc[k] * Zt[k * 128 + j];
    ((float*)(ws + OFF_M))[c * 128 + j] = a;
}

// K7: loss
extern "C" __global__ __launch_bounds__(256)
void k7_loss(char* __restrict__ ws, float* __restrict__ out)
{
    __shared__ float norms[128];
    __shared__ int pres[128];
    __shared__ float wsum[4];
    const int tid = threadIdx.x;
    const float* M = (const float*)(ws + OFF_M);
    const int* counts = (const int*)(ws + OFF_COUNTS);
    if (tid < 128) {
        int p = counts[tid] > 0;
        pres[tid] = p;
        norms[tid] = sqrtf(p ? M[tid * 129] : 1.0f);
    }
    __syncthreads();
    float ls = 0.f;
    for (int idx = tid; idx < 16384; idx += 256) {
        int c = idx >> 7, j = idx & 127;
        if (c != j && pres[c] && pres[j])
            ls += 1.0f - M[idx] / ((norms[c] + EPSF) * (norms[j] + EPSF));
    }
    #pragma unroll
    for (int off = 32; off > 0; off >>= 1) ls += __shfl_down(ls, off);
    if ((tid & 63) == 0) wsum[tid >> 6] = ls;
    __syncthreads();
    if (tid == 0) {
        int np = 0;
        for (int c = 0; c < 128; ++c) np += pres[c];
        float tot = wsum[0] + wsum[1] + wsum[2] + wsum[3];
        out[0] = (np >= 2) ? tot : 0.0f;
    }
}

// ---------------------------------------------------------------------------
extern "C" void kernel_launch(void* const* d_in, const int* in_sizes, int n_in,
                              void* d_out, int out_size, void* d_ws, size_t ws_size,
                              hipStream_t stream)
{
    const float* logits = (const float*)d_in[0];
    const float* img    = (const float*)d_in[1];
    const float* T      = (const float*)d_in[2];
    const void*  mask   = d_in[3];
    char* ws = (char*)d_ws;

    size_t avail = (ws_size > (size_t)OFF_BIG) ? ws_size - OFF_BIG : 0;
    int nSlab = (int)(avail / 131072);   // 128 KB per slab
    if (nSlab > 256) nSlab = 256;
    if (nSlab < 1) nSlab = 1;

    hipMemsetAsync(ws + OFF_COUNTS, 0, 512, stream);
    if (nSlab < 256)
        hipMemsetAsync(ws + OFF_BIG, 0, (size_t)nSlab * 131072, stream);

    kg_gram<<<4, 1024, 0, stream>>>(T, ws);                // G + T^T
    kx<<<257, 1024, 0, stream>>>(logits, img, mask, ws, nSlab); // fused pass + GJ
    kr_sums<<<256, 128, 0, stream>>>(ws, nSlab);           // slab reduce -> sums
    k4_B<<<128, 128, 0, stream>>>(ws);
    k5_Z<<<128, 128, 0, stream>>>(ws);
    k6_M<<<128, 128, 0, stream>>>(ws);
    k7_loss<<<1, 256, 0, stream>>>(ws, (float*)d_out);
}

// Round 12
// 360.032 us; speedup vs baseline: 1.2335x; 1.2335x over previous
//
#include <hip/hip_runtime.h>

// Problem constants
#define NSAMP 262144
#define CCLS 128
#define DDIM 256
#define EPSF 1e-8f

// ws byte offsets
#define OFF_COUNTS 0u         // 128 * u32
#define OFF_SUMS   2048u      // 128x256 f32 sums (natural layout)
#define OFF_G      133120u    // 128x128 f32
#define OFF_W      198656u    // 128x128 f32 (G^-1)
#define OFF_TT     264192u    // 256x128 f32 (T transposed)
#define OFF_B      395264u    // 128x128 f32 (means @ T^T)
#define OFF_ZT     460800u    // 128x128 f32 (W @ B^T)
#define OFF_M      526336u    // 128x128 f32 (B W B^T)
#define OFF_LAB    1048576u   // 262144 u8 labels (255 = ungated, via memset 0xFF)
#define OFF_BIG    1644288u   // slabs: 512 x 16384 f32 (64KB each) = 33.5 MB

// ---------------------------------------------------------------------------
// KG: 4 blocks x 1024. Block g computes rows [32g,32g+32) of G = T*T^T and
//     writes T^T chunk g. (verbatim verified)
// ---------------------------------------------------------------------------
extern "C" __global__ __launch_bounds__(1024)
void kg_gram(const float* __restrict__ T, char* __restrict__ ws)
{
    __shared__ float Tl[64][132];
    const int g = blockIdx.x, tid = threadIdx.x;
    float* Tt = (float*)(ws + OFF_TT);
    float* G  = (float*)(ws + OFF_G);
    float a0[8], a1[8];
    #pragma unroll
    for (int j = 0; j < 8; ++j) { a0[j] = 0.f; a1[j] = 0.f; }
    const int Lr = 2 * (tid >> 4);
    const int c0 = 8 * (tid & 15);
    for (int ch = 0; ch < 4; ++ch) {
        for (int i = tid; i < 8192; i += 1024) {
            int cc = i >> 6, dd = i & 63;
            Tl[dd][cc] = T[cc * 256 + ch * 64 + dd];
        }
        __syncthreads();
        if (g == ch) {
            for (int i = tid; i < 8192; i += 1024) {
                int c2 = i & 127, d2 = i >> 7;
                Tt[(ch * 64 + d2) * 128 + c2] = Tl[d2][c2];
            }
        }
        if (tid < 256) {
            for (int dd = 0; dd < 64; ++dd) {
                float r0 = Tl[dd][32 * g + Lr];
                float r1 = Tl[dd][32 * g + Lr + 1];
                float cv[8];
                *(float4*)&cv[0] = *(const float4*)&Tl[dd][c0];
                *(float4*)&cv[4] = *(const float4*)&Tl[dd][c0 + 4];
                #pragma unroll
                for (int j = 0; j < 8; ++j) { a0[j] += r0 * cv[j]; a1[j] += r1 * cv[j]; }
            }
        }
        __syncthreads();
    }
    if (tid < 256) {
        int gr = 32 * g + Lr;
        *(float4*)&G[gr * 128 + c0]           = make_float4(a0[0], a0[1], a0[2], a0[3]);
        *(float4*)&G[gr * 128 + c0 + 4]       = make_float4(a0[4], a0[5], a0[6], a0[7]);
        *(float4*)&G[(gr + 1) * 128 + c0]     = make_float4(a1[0], a1[1], a1[2], a1[3]);
        *(float4*)&G[(gr + 1) * 128 + c0 + 4] = make_float4(a1[4], a1[5], a1[6], a1[7]);
    }
}

// ---------------------------------------------------------------------------
// KLABINV: 257 blocks x 1024 thr, tiny LDS => >=2 blocks/CU => ALL blocks
//   resident from t=0 (grid 257 <= 512 slots), so block 256's Gauss-Jordan
//   runs fully OVERLAPPED with the label sweep (r11 lesson: with 1-block/CU
//   LDS the 257th block became a serial +83us tail).
//   Blocks 0..255: GATED-ONLY argmax (67MB logits instead of 134MB). Wave
//   owns 64 samples; gated samples processed 4-at-a-time by 16-lane
//   subgroups, 1-deep software pipeline. Ungated labels stay 255 (memset).
//   Block 256: GJ inversion of G -> W, 4x4 tile/thread (16-reg static array
//   => cannot spill at any occupancy cap; verified in r9/r10).
// ---------------------------------------------------------------------------
extern "C" __global__ __launch_bounds__(1024)
void klabinv(const float* __restrict__ logits, const void* __restrict__ mask,
             char* __restrict__ ws)
{
    __shared__ float prA[128], prB[128], pcA[128], pcB[128];
    __shared__ int sIsBool;
    const int tid = threadIdx.x;

    if (blockIdx.x == 256) {
        // ---- Gauss-Jordan inversion, 1024 threads, 4x4 tiles ----
        const float* G = (const float*)(ws + OFF_G);
        float* W = (float*)(ws + OFF_W);
        float gg[4][4];
        const int r0 = 4 * (tid >> 5), c0 = 4 * (tid & 31);
        #pragma unroll
        for (int ii = 0; ii < 4; ++ii)
            *(float4*)&gg[ii][0] = *(const float4*)&G[(r0 + ii) * 128 + c0];
        if (r0 == 0) {
            #pragma unroll
            for (int j = 0; j < 4; ++j) prA[c0 + j] = gg[0][j];
        }
        if (c0 == 0) {
            #pragma unroll
            for (int i = 0; i < 4; ++i) pcA[r0 + i] = gg[i][0];
        }
        __syncthreads();
        for (int k = 0; k < 128; ++k) {
            const float* pr = (k & 1) ? prB : prA;
            const float* pc = (k & 1) ? pcB : pcA;
            float rinv = 1.0f / pr[k];
            float4 ra = *(const float4*)&pr[c0];
            float4 fa = *(const float4*)&pc[r0];
            float rf[4] = { ra.x, ra.y, ra.z, ra.w };
            float fcv[4] = { fa.x, fa.y, fa.z, fa.w };
            #pragma unroll
            for (int j = 0; j < 4; ++j) rf[j] = (c0 + j == k) ? rinv : rf[j] * rinv;
            #pragma unroll
            for (int i = 0; i < 4; ++i) {
                if (r0 + i == k) {
                    #pragma unroll
                    for (int j = 0; j < 4; ++j) gg[i][j] = rf[j];
                } else {
                    float f = fcv[i];
                    #pragma unroll
                    for (int j = 0; j < 4; ++j) {
                        float base = (c0 + j == k) ? 0.0f : gg[i][j];
                        gg[i][j] = base - f * rf[j];
                    }
                }
            }
            const int kn = k + 1;
            if (kn < 128) {
                float* prn = (kn & 1) ? prB : prA;
                float* pcn = (kn & 1) ? pcB : pcA;
                #pragma unroll
                for (int ii = 0; ii < 4; ++ii) {
                    if (r0 + ii == kn) {
                        #pragma unroll
                        for (int j = 0; j < 4; ++j) prn[c0 + j] = gg[ii][j];
                    }
                }
                #pragma unroll
                for (int jj = 0; jj < 4; ++jj) {
                    if (c0 + jj == kn) {
                        #pragma unroll
                        for (int i = 0; i < 4; ++i) pcn[r0 + i] = gg[i][jj];
                    }
                }
            }
            __syncthreads();
        }
        #pragma unroll
        for (int ii = 0; ii < 4; ++ii)
            *(float4*)&W[(r0 + ii) * 128 + c0] = *(float4*)&gg[ii][0];
        return;
    }

    // ---- gated-argmax blocks ----
    unsigned char* labels = (unsigned char*)(ws + OFF_LAB);
    { // mask dtype sniff
        int v = 0;
        if (tid < 64) v = ((const int*)mask)[tid];
        unsigned long long bal = __ballot((unsigned)v > 1u);
        if (tid == 0) sIsBool = (bal != 0ull);
    }
    __syncthreads();
    const bool isBool = (sIsBool != 0);

    const int wave = tid >> 6, lane = tid & 63;
    const int base = blockIdx.x * 1024 + wave * 64;   // 64 samples per wave
    const int sg = lane >> 4, l16 = lane & 15;
    const float4* lp4 = (const float4*)logits;        // 32 float4 per row

    int gv = isBool ? (int)((const unsigned char*)mask)[base + lane]
                    : ((const int*)mask)[base + lane];
    unsigned long long gm = __ballot(gv != 0);

    // prologue: extract group 0 (up to 4 gated samples) + issue loads
    int cb0 = 0, cb1 = 0, cb2 = 0, cb3 = 0, cn = 0;
    {
        unsigned long long t = gm;
        if (t) { cb0 = (int)(__ffsll((long long)t) - 1); t &= t - 1; ++cn; }
        if (t) { cb1 = (int)(__ffsll((long long)t) - 1); t &= t - 1; ++cn; }
        if (t) { cb2 = (int)(__ffsll((long long)t) - 1); t &= t - 1; ++cn; }
        if (t) { cb3 = (int)(__ffsll((long long)t) - 1); t &= t - 1; ++cn; }
        gm = t;
    }
    int myS = base + ((sg == 0) ? cb0 : (sg == 1) ? cb1 : (sg == 2) ? cb2 : cb3);
    float4 A, B4;
    if (cn) { A = lp4[(size_t)myS * 32 + l16]; B4 = lp4[(size_t)myS * 32 + 16 + l16]; }

    while (cn > 0) {
        // extract next group + issue its loads (overlap with current reduce)
        int nb0 = 0, nb1 = 0, nb2 = 0, nb3 = 0, nn = 0;
        {
            unsigned long long t = gm;
            if (t) { nb0 = (int)(__ffsll((long long)t) - 1); t &= t - 1; ++nn; }
            if (t) { nb1 = (int)(__ffsll((long long)t) - 1); t &= t - 1; ++nn; }
            if (t) { nb2 = (int)(__ffsll((long long)t) - 1); t &= t - 1; ++nn; }
            if (t) { nb3 = (int)(__ffsll((long long)t) - 1); t &= t - 1; ++nn; }
            gm = t;
        }
        int nS = base + ((sg == 0) ? nb0 : (sg == 1) ? nb1 : (sg == 2) ? nb2 : nb3);
        float4 nA, nB;
        if (nn) { nA = lp4[(size_t)nS * 32 + l16]; nB = lp4[(size_t)nS * 32 + 16 + l16]; }

        // reduce current: lane holds dims [4*l16,4*l16+4) and [64+4*l16,...)
        float m = A.x; int id = 4 * l16;
        if (A.y > m) { m = A.y; id = 4 * l16 + 1; }
        if (A.z > m) { m = A.z; id = 4 * l16 + 2; }
        if (A.w > m) { m = A.w; id = 4 * l16 + 3; }
        if (B4.x > m) { m = B4.x; id = 64 + 4 * l16; }
        if (B4.y > m) { m = B4.y; id = 64 + 4 * l16 + 1; }
        if (B4.z > m) { m = B4.z; id = 64 + 4 * l16 + 2; }
        if (B4.w > m) { m = B4.w; id = 64 + 4 * l16 + 3; }
        #pragma unroll
        for (int off = 1; off < 16; off <<= 1) {
            float om = __shfl_xor(m, off);
            int   oi = __shfl_xor(id, off);
            if (om > m || (om == m && oi < id)) { m = om; id = oi; }
        }
        if (l16 == 0 && sg < cn) labels[myS] = (unsigned char)id;

        cn = nn; myS = nS; A = nA; B4 = nB;
    }
}

// ---------------------------------------------------------------------------
// KSEG: 512 blocks = (256 sample-ranges x 2 D-halves), 1024 thr. Wave w owns
//       8-class octet [8w,8w+8); accumulators in 16 statically-indexed VGPRs.
//       In-register label broadcast via __shfl; per-chunk label prefetch;
//       plain coalesced float2 stores into per-block 64KB slab.
//       (r7/r9 verified body — measured clean for the first time this round)
// ---------------------------------------------------------------------------
extern "C" __global__ __launch_bounds__(1024)
void kseg(const float* __restrict__ img, char* __restrict__ ws, int nPair)
{
    const int tid = threadIdx.x, b = blockIdx.x;
    const int range = b >> 1, h = b & 1;        // sample range x D-half
    const int wave = tid >> 6, lane = tid & 63;
    const unsigned char* labels = (const unsigned char*)(ws + OFF_LAB);
    const float2* im2 = (const float2*)img;     // 128 float2 per row
    const int sbase = range * 1024;

    float accx[8], accy[8]; int cnt[8];
    #pragma unroll
    for (int c = 0; c < 8; ++c) { accx[c] = 0.f; accy[c] = 0.f; cnt[c] = 0; }

    int lab = labels[sbase + lane];             // chunk-0 labels
    for (int ch = 0; ch < 16; ++ch) {
        const int nch = (ch + 1 < 16) ? ch + 1 : 15;        // clamped prefetch
        const int labn = labels[sbase + nch * 64 + lane];
        const int s64 = sbase + ch * 64;
        unsigned long long mb = __ballot((lab >> 3) == wave);   // my octet (255>>3=31 excluded)
        while (mb) {
            int bit = (int)(__ffsll((long long)mb) - 1); mb &= mb - 1;
            int lc = __shfl(lab, bit) & 7;                  // in-register broadcast
            float2 v = im2[(size_t)(s64 + bit) * 128 + h * 64 + lane];
            #pragma unroll
            for (int c = 0; c < 8; ++c) {
                bool p = (lc == c);
                accx[c] += p ? v.x : 0.f;
                accy[c] += p ? v.y : 0.f;
                cnt[c]  += p ? 1 : 0;
            }
        }
        lab = labn;
    }

    // flush: plain coalesced stores into own slab (nPair==256), else atomics
    if (nPair == 256) {
        float2* slab = (float2*)((float*)(ws + OFF_BIG) + (size_t)b * 16384);
        #pragma unroll
        for (int c = 0; c < 8; ++c)
            slab[(wave * 8 + c) * 64 + lane] = make_float2(accx[c], accy[c]);
    } else {
        float* slab = (float*)(ws + OFF_BIG) + (size_t)((range % nPair) * 2 + h) * 16384;
        #pragma unroll
        for (int c = 0; c < 8; ++c) {
            unsafeAtomicAdd(&slab[(wave * 8 + c) * 128 + 2 * lane],     accx[c]);
            unsafeAtomicAdd(&slab[(wave * 8 + c) * 128 + 2 * lane + 1], accy[c]);
        }
    }
    if (h == 0 && lane == 0) {
        int* counts = (int*)(ws + OFF_COUNTS);
        #pragma unroll
        for (int c = 0; c < 8; ++c)
            if (cnt[c]) atomicAdd(&counts[wave * 8 + c], cnt[c]);
    }
}

// ---------------------------------------------------------------------------
// KR: deterministic slab reduction -> sums[cls][d] (natural). 256 blk x 128.
// ---------------------------------------------------------------------------
extern "C" __global__ __launch_bounds__(128)
void kr_sums(char* __restrict__ ws, int nPair)
{
    const int idx = blockIdx.x * 128 + threadIdx.x;   // [0, 32768)
    const int cls = idx >> 8, rem = idx & 255;
    const int h = rem >> 7, dh = rem & 127;
    const float* base = (const float*)(ws + OFF_BIG) + (size_t)h * 16384 + cls * 128 + dh;
    float a = 0.f;
    for (int r = 0; r < nPair; ++r) a += base[(size_t)r * 32768];
    ((float*)(ws + OFF_SUMS))[cls * 256 + h * 128 + dh] = a;
}

// K4: B = (sums/counts) @ T^T  (mean-divide fused)
extern "C" __global__ __launch_bounds__(128)
void k4_B(char* __restrict__ ws)
{
    __shared__ float mr[256];
    const int c = blockIdx.x, j = threadIdx.x;
    const float* sums = (const float*)(ws + OFF_SUMS);
    const int* counts = (const int*)(ws + OFF_COUNTS);
    const float* Tt = (const float*)(ws + OFF_TT);
    float rcp = 1.0f / fmaxf((float)counts[c], 1.0f);
    mr[j] = sums[c * 256 + j] * rcp;
    mr[j + 128] = sums[c * 256 + 128 + j] * rcp;
    __syncthreads();
    float a = 0.f;
    #pragma unroll 8
    for (int d = 0; d < 256; ++d) a += mr[d] * Tt[d * 128 + j];
    ((float*)(ws + OFF_B))[c * 128 + j] = a;
}

// K5: Zt = (B @ W)^T = W @ B^T   (W symmetric)
extern "C" __global__ __launch_bounds__(128)
void k5_Z(char* __restrict__ ws)
{
    __shared__ float bc[128];
    const int c = blockIdx.x, j = threadIdx.x;
    const float* B = (const float*)(ws + OFF_B);
    const float* W = (const float*)(ws + OFF_W);
    bc[j] = B[c * 128 + j];
    __syncthreads();
    float a = 0.f;
    #pragma unroll 8
    for (int k = 0; k < 128; ++k) a += bc[k] * W[k * 128 + j];
    ((float*)(ws + OFF_ZT))[j * 128 + c] = a;
}

// K6: M = B @ Zt = B W B^T
extern "C" __global__ __launch_bounds__(128)
void k6_M(char* __restrict__ ws)
{
    __shared__ float bc[128];
    const int c = blockIdx.x, j = threadIdx.x;
    const float* B = (const float*)(ws + OFF_B);
    const float* Zt = (const float*)(ws + OFF_ZT);
    bc[j] = B[c * 128 + j];
    __syncthreads();
    float a = 0.f;
    #pragma unroll 8
    for (int k = 0; k < 128; ++k) a += bc[k] * Zt[k * 128 + j];
    ((float*)(ws + OFF_M))[c * 128 + j] = a;
}

// K7: loss
extern "C" __global__ __launch_bounds__(256)
void k7_loss(char* __restrict__ ws, float* __restrict__ out)
{
    __shared__ float norms[128];
    __shared__ int pres[128];
    __shared__ float wsum[4];
    const int tid = threadIdx.x;
    const float* M = (const float*)(ws + OFF_M);
    const int* counts = (const int*)(ws + OFF_COUNTS);
    if (tid < 128) {
        int p = counts[tid] > 0;
        pres[tid] = p;
        norms[tid] = sqrtf(p ? M[tid * 129] : 1.0f);
    }
    __syncthreads();
    float ls = 0.f;
    for (int idx = tid; idx < 16384; idx += 256) {
        int c = idx >> 7, j = idx & 127;
        if (c != j && pres[c] && pres[j])
            ls += 1.0f - M[idx] / ((norms[c] + EPSF) * (norms[j] + EPSF));
    }
    #pragma unroll
    for (int off = 32; off > 0; off >>= 1) ls += __shfl_down(ls, off);
    if ((tid & 63) == 0) wsum[tid >> 6] = ls;
    __syncthreads();
    if (tid == 0) {
        int np = 0;
        for (int c = 0; c < 128; ++c) np += pres[c];
        float tot = wsum[0] + wsum[1] + wsum[2] + wsum[3];
        out[0] = (np >= 2) ? tot : 0.0f;
    }
}

// ---------------------------------------------------------------------------
extern "C" void kernel_launch(void* const* d_in, const int* in_sizes, int n_in,
                              void* d_out, int out_size, void* d_ws, size_t ws_size,
                              hipStream_t stream)
{
    const float* logits = (const float*)d_in[0];
    const float* img    = (const float*)d_in[1];
    const float* T      = (const float*)d_in[2];
    const void*  mask   = d_in[3];
    char* ws = (char*)d_ws;

    size_t avail = (ws_size > (size_t)OFF_BIG) ? ws_size - OFF_BIG : 0;
    int nPair = (int)(avail / 131072);   // a pair = 2 slabs x 64KB (h=0,1)
    if (nPair > 256) nPair = 256;
    if (nPair < 1) nPair = 1;

    hipMemsetAsync(ws + OFF_COUNTS, 0, 512, stream);
    hipMemsetAsync(ws + OFF_LAB, 0xFF, NSAMP, stream);     // ungated = 255
    if (nPair < 256)
        hipMemsetAsync(ws + OFF_BIG, 0, (size_t)nPair * 131072, stream);

    kg_gram<<<4, 1024, 0, stream>>>(T, ws);                 // G + T^T
    klabinv<<<257, 1024, 0, stream>>>(logits, mask, ws);    // gated labels ∥ GJ inv
    kseg<<<512, 1024, 0, stream>>>(img, ws, nPair);         // reg-octet gather
    kr_sums<<<256, 128, 0, stream>>>(ws, nPair);            // slab reduce -> sums
    k4_B<<<128, 128, 0, stream>>>(ws);
    k5_Z<<<128, 128, 0, stream>>>(ws);
    k6_M<<<128, 128, 0, stream>>>(ws);
    k7_loss<<<1, 256, 0, stream>>>(ws, (float*)d_out);
}